// Round 1
// baseline (11434.080 us; speedup 1.0000x reference)
//
#include <hip/hip_runtime.h>

#define NA   16384   // n_angles * N
#define NN   2048    // N
#define CIN  16
#define COUT 32
#define NANG 8
#define KCH  15

__device__ __forceinline__ float f4_get(const float4& v, int i) {
    return i == 0 ? v.x : i == 1 ? v.y : i == 2 ? v.z : v.w;
}

// Build T0 = tile(x, (NANG,1)) : T0[a*NN + n][ci] = x[n][ci]
__global__ __launch_bounds__(256) void k_tile(const float* __restrict__ x,
                                              float* __restrict__ T0) {
    int idx = blockIdx.x * 256 + threadIdx.x;
    if (idx >= NA * CIN) return;
    int row = idx >> 4;          // 0..NA-1
    int ci  = idx & 15;
    int n   = row & (NN - 1);    // row % NN
    T0[idx] = x[n * CIN + ci];
}

// Tnew = alpha * (Ls @ Tcur) + beta * Tprev
// block: 256 threads, handles 4 consecutive rows of Ls across all 16384 cols
__global__ __launch_bounds__(256) void k_spmm(const float* __restrict__ Ls,
                                              const float* __restrict__ Tcur,
                                              const float* __restrict__ Tprev,
                                              float* __restrict__ Tnew,
                                              float alpha, float beta) {
    const int t  = threadIdx.x;
    const int r0 = blockIdx.x * 4;
    const float* L0 = Ls + (size_t)r0 * NA;

    float acc[4][16];
    #pragma unroll
    for (int i = 0; i < 4; ++i)
        #pragma unroll
        for (int j = 0; j < 16; ++j) acc[i][j] = 0.f;

    // 16 iterations: each thread handles 4 consecutive c per iteration,
    // wave covers 4*64=256 consecutive c -> fully coalesced float4 Ls loads
    #pragma unroll 1
    for (int it = 0; it < NA / (256 * 4); ++it) {
        const int c4 = (it * 256 + t) * 4;
        float4 l[4];
        #pragma unroll
        for (int r = 0; r < 4; ++r)
            l[r] = *(const float4*)(L0 + (size_t)r * NA + c4);
        #pragma unroll
        for (int cc = 0; cc < 4; ++cc) {
            const float4* tv = (const float4*)(Tcur + (size_t)(c4 + cc) * CIN);
            const float4 t0 = tv[0], t1 = tv[1], t2 = tv[2], t3 = tv[3];
            const float tj[16] = {t0.x, t0.y, t0.z, t0.w, t1.x, t1.y, t1.z, t1.w,
                                  t2.x, t2.y, t2.z, t2.w, t3.x, t3.y, t3.z, t3.w};
            #pragma unroll
            for (int j = 0; j < 16; ++j) {
                const float tvj = tj[j];
                #pragma unroll
                for (int r = 0; r < 4; ++r)
                    acc[r][j] = fmaf(f4_get(l[r], cc), tvj, acc[r][j]);
            }
        }
    }

    // reduce across 256 threads: wave shfl_down reduce -> LDS -> 4-wave sum
    __shared__ float red[4][64];
    const int wave = t >> 6;
    const int lane = t & 63;
    #pragma unroll
    for (int i = 0; i < 4; ++i)
        #pragma unroll
        for (int j = 0; j < 16; ++j) {
            float v = acc[i][j];
            #pragma unroll
            for (int off = 32; off > 0; off >>= 1)
                v += __shfl_down(v, off, 64);
            if (lane == 0) red[wave][i * 16 + j] = v;   // compile-time index
        }
    __syncthreads();
    if (t < 64) {
        const float s = red[0][t] + red[1][t] + red[2][t] + red[3][t];
        const int rr = r0 + (t >> 4);
        const int jj = t & 15;
        float v = alpha * s;
        if (beta != 0.f) v += beta * Tprev[rr * CIN + jj];
        Tnew[rr * CIN + jj] = v;
    }
}

// out[n][co] (+)= sum_a sum_ci T[a*NN+n][ci] * W[(a*CIN+ci)*COUT + co]  (+ bias)
__global__ __launch_bounds__(256) void k_proj(const float* __restrict__ T,
                                              const float* __restrict__ W,
                                              const float* __restrict__ bias,
                                              float* __restrict__ out, int add) {
    int idx = blockIdx.x * 256 + threadIdx.x;
    if (idx >= NN * COUT) return;
    const int n  = idx >> 5;
    const int co = idx & 31;
    float s = add ? out[idx] : bias[co];
    #pragma unroll
    for (int a = 0; a < NANG; ++a) {
        const float* Trow = T + (size_t)(a * NN + n) * CIN;
        const float* Wb   = W + (size_t)(a * CIN) * COUT + co;
        #pragma unroll
        for (int ci = 0; ci < CIN; ++ci)
            s = fmaf(Trow[ci], Wb[ci * COUT], s);
    }
    out[idx] = s;
}

extern "C" void kernel_launch(void* const* d_in, const int* in_sizes, int n_in,
                              void* d_out, int out_size, void* d_ws, size_t ws_size,
                              hipStream_t stream) {
    const float* x    = (const float*)d_in[0];
    const float* Ls   = (const float*)d_in[1];
    const float* W    = (const float*)d_in[2];
    const float* bias = (const float*)d_in[3];
    float* out = (float*)d_out;
    float* ws  = (float*)d_ws;

    const size_t TSZ = (size_t)NA * CIN;           // 262144 floats = 1 MiB
    float* buf[3] = { ws, ws + TSZ, ws + 2 * TSZ };

    const int WSTRIDE = (NANG * CIN) * COUT;       // 128*32 per k

    // k = 0
    k_tile<<<(NA * CIN + 255) / 256, 256, 0, stream>>>(x, buf[0]);
    k_proj<<<(NN * COUT + 255) / 256, 256, 0, stream>>>(buf[0], W, bias, out, 0);

    // k = 1 : T1 = Ls @ T0
    k_spmm<<<NA / 4, 256, 0, stream>>>(Ls, buf[0], buf[0], buf[1], 1.f, 0.f);
    k_proj<<<(NN * COUT + 255) / 256, 256, 0, stream>>>(buf[1], W + WSTRIDE, bias, out, 1);

    // k = 2..14 : T2 = 2*(Ls @ T1) - T0
    int prev = 0, cur = 1;
    for (int k = 2; k < KCH; ++k) {
        int nxt = 3 - cur - prev;
        k_spmm<<<NA / 4, 256, 0, stream>>>(Ls, buf[cur], buf[prev], buf[nxt], 2.f, -1.f);
        k_proj<<<(NN * COUT + 255) / 256, 256, 0, stream>>>(buf[nxt], W + (size_t)k * WSTRIDE,
                                                            bias, out, 1);
        prev = cur; cur = nxt;
    }
}

// Round 2
// 4858.641 us; speedup vs baseline: 2.3533x; 2.3533x over previous
//
#include <hip/hip_runtime.h>

#define NA   16384   // n_angles * N
#define NN   2048    // N
#define CIN  16
#define COUT 32
#define NANG 8
#define KCH  15
#define RPB  8       // Ls rows per block

__device__ __forceinline__ float f4_get(const float4& v, int i) {
    return i == 0 ? v.x : i == 1 ? v.y : i == 2 ? v.z : v.w;
}

// Build T0^T : Tt0[j][a*NN + n] = x[n][j]   (Tt layout: [CIN][NA])
__global__ __launch_bounds__(256) void k_tile_t(const float* __restrict__ x,
                                                float* __restrict__ Tt0) {
    int idx = blockIdx.x * 256 + threadIdx.x;   // over CIN*NA
    if (idx >= CIN * NA) return;
    int j = idx >> 14;           // idx / NA
    int c = idx & (NA - 1);
    int n = c & (NN - 1);
    Tt0[idx] = x[n * CIN + j];
}

// Tt_new = alpha * (Ls @ T)^T + beta * Tt_prev    (all T buffers [CIN][NA])
// block: 256 threads, RPB consecutive rows of Ls, full 16384-col sweep.
// All global loads (Ls and Tt) are lane-coalesced float4.
__global__ __launch_bounds__(256, 2) void k_spmm_t(const float* __restrict__ Ls,
                                                   const float* __restrict__ Tt,
                                                   const float* __restrict__ Tp,
                                                   float* __restrict__ Tn,
                                                   float alpha, float beta) {
    const int t  = threadIdx.x;
    const int r0 = blockIdx.x * RPB;
    const float* L0 = Ls + (size_t)r0 * NA;

    float acc[RPB][16];
    #pragma unroll
    for (int r = 0; r < RPB; ++r)
        #pragma unroll
        for (int j = 0; j < 16; ++j) acc[r][j] = 0.f;

    #pragma unroll 1
    for (int it = 0; it < NA / (256 * 4); ++it) {   // 16 iterations
        const int c4 = (it * 256 + t) * 4;
        float4 l[RPB];
        #pragma unroll
        for (int r = 0; r < RPB; ++r)
            l[r] = *(const float4*)(L0 + (size_t)r * NA + c4);
        // T^T rows in two halves of 8 to bound live registers
        #pragma unroll
        for (int h = 0; h < 2; ++h) {
            float4 tv[8];
            #pragma unroll
            for (int jj = 0; jj < 8; ++jj)
                tv[jj] = *(const float4*)(Tt + (size_t)(h * 8 + jj) * NA + c4);
            #pragma unroll
            for (int cc = 0; cc < 4; ++cc)
                #pragma unroll
                for (int jj = 0; jj < 8; ++jj) {
                    const float tvj = f4_get(tv[jj], cc);
                    #pragma unroll
                    for (int r = 0; r < RPB; ++r)
                        acc[r][h * 8 + jj] = fmaf(f4_get(l[r], cc), tvj,
                                                  acc[r][h * 8 + jj]);
                }
        }
    }

    // reduce 256 threads -> RPB*16 sums
    __shared__ float red[4][RPB * 16];
    const int wave = t >> 6;
    const int lane = t & 63;
    #pragma unroll
    for (int r = 0; r < RPB; ++r)
        #pragma unroll
        for (int j = 0; j < 16; ++j) {
            float v = acc[r][j];
            #pragma unroll
            for (int off = 32; off > 0; off >>= 1)
                v += __shfl_down(v, off, 64);
            if (lane == 0) red[wave][r * 16 + j] = v;
        }
    __syncthreads();
    if (t < RPB * 16) {
        const float s = red[0][t] + red[1][t] + red[2][t] + red[3][t];
        const int rr = t >> 4;          // row within block
        const int jj = t & 15;          // channel
        float v = alpha * s;
        if (beta != 0.f) v += beta * Tp[(size_t)jj * NA + r0 + rr];
        Tn[(size_t)jj * NA + r0 + rr] = v;
    }
}

// out[n][co] (+)= sum_a sum_ci Tt[ci][a*NN+n] * W[(a*CIN+ci)*COUT + co]
__global__ __launch_bounds__(256) void k_proj_t(const float* __restrict__ Tt,
                                                const float* __restrict__ W,
                                                const float* __restrict__ bias,
                                                float* __restrict__ out, int add) {
    int idx = blockIdx.x * 256 + threadIdx.x;
    if (idx >= NN * COUT) return;
    const int n  = idx >> 5;
    const int co = idx & 31;
    float s = add ? out[idx] : bias[co];
    #pragma unroll
    for (int a = 0; a < NANG; ++a)
        #pragma unroll
        for (int ci = 0; ci < CIN; ++ci)
            s = fmaf(Tt[(size_t)ci * NA + a * NN + n],
                     W[(size_t)(a * CIN + ci) * COUT + co], s);
    out[idx] = s;
}

extern "C" void kernel_launch(void* const* d_in, const int* in_sizes, int n_in,
                              void* d_out, int out_size, void* d_ws, size_t ws_size,
                              hipStream_t stream) {
    const float* x    = (const float*)d_in[0];
    const float* Ls   = (const float*)d_in[1];
    const float* W    = (const float*)d_in[2];
    const float* bias = (const float*)d_in[3];
    float* out = (float*)d_out;
    float* ws  = (float*)d_ws;

    const size_t TSZ = (size_t)NA * CIN;           // 1 MiB each
    float* buf[3] = { ws, ws + TSZ, ws + 2 * TSZ };
    const int WSTRIDE = (NANG * CIN) * COUT;

    // k = 0
    k_tile_t<<<(CIN * NA + 255) / 256, 256, 0, stream>>>(x, buf[0]);
    k_proj_t<<<(NN * COUT + 255) / 256, 256, 0, stream>>>(buf[0], W, bias, out, 0);

    // k = 1 : T1 = Ls @ T0
    k_spmm_t<<<NA / RPB, 256, 0, stream>>>(Ls, buf[0], buf[0], buf[1], 1.f, 0.f);
    k_proj_t<<<(NN * COUT + 255) / 256, 256, 0, stream>>>(buf[1], W + WSTRIDE, bias, out, 1);

    // k = 2..14 : T2 = 2*(Ls @ T1) - T0
    int prev = 0, cur = 1;
    for (int k = 2; k < KCH; ++k) {
        int nxt = 3 - cur - prev;
        k_spmm_t<<<NA / RPB, 256, 0, stream>>>(Ls, buf[cur], buf[prev], buf[nxt], 2.f, -1.f);
        k_proj_t<<<(NN * COUT + 255) / 256, 256, 0, stream>>>(buf[nxt], W + (size_t)k * WSTRIDE,
                                                              bias, out, 1);
        prev = cur; cur = nxt;
    }
}

// Round 3
// 4543.182 us; speedup vs baseline: 2.5168x; 1.0694x over previous
//
#include <hip/hip_runtime.h>
#include <hip/hip_fp16.h>

#define NA   16384   // n_angles * N
#define NN   2048    // N
#define CIN  16
#define COUT 32
#define NANG 8
#define KCH  15
#define RPB  8       // Ls rows per block

__device__ __forceinline__ float f4_get(const float4& v, int i) {
    return i == 0 ? v.x : i == 1 ? v.y : i == 2 ? v.z : v.w;
}

// ---- Ls fp32 -> fp16 (one-time per call; Ls values ~N(0,1/128^2), fp16-safe)
__global__ __launch_bounds__(256) void k_conv(const float* __restrict__ Ls,
                                              __half* __restrict__ Lh) {
    const size_t total = (size_t)NA * NA;
    const size_t stride = (size_t)gridDim.x * 256 * 8;
    for (size_t i = ((size_t)blockIdx.x * 256 + threadIdx.x) * 8; i < total; i += stride) {
        float4 a = *(const float4*)(Ls + i);
        float4 b = *(const float4*)(Ls + i + 4);
        __half2 h0 = __floats2half2_rn(a.x, a.y);
        __half2 h1 = __floats2half2_rn(a.z, a.w);
        __half2 h2 = __floats2half2_rn(b.x, b.y);
        __half2 h3 = __floats2half2_rn(b.z, b.w);
        uint4 o;
        o.x = *(unsigned*)&h0; o.y = *(unsigned*)&h1;
        o.z = *(unsigned*)&h2; o.w = *(unsigned*)&h3;
        *(uint4*)(Lh + i) = o;
    }
}

// Build T0^T : Tt0[j][a*NN + n] = x[n][j]   (Tt layout: [CIN][NA], fp32)
__global__ __launch_bounds__(256) void k_tile_t(const float* __restrict__ x,
                                                float* __restrict__ Tt0) {
    int idx = blockIdx.x * 256 + threadIdx.x;
    if (idx >= CIN * NA) return;
    int j = idx >> 14;
    int c = idx & (NA - 1);
    int n = c & (NN - 1);
    Tt0[idx] = x[n * CIN + j];
}

// Tt_new = alpha * (Lh @ T)^T + beta * Tt_prev    (T buffers [CIN][NA] fp32)
// 256 threads, RPB rows of Ls, full 16384-col sweep; Ls loads are 8B fp16x4,
// register-double-buffered one iteration ahead.
__global__ __launch_bounds__(256, 2) void k_spmm_h(const __half* __restrict__ Lh,
                                                   const float* __restrict__ Tt,
                                                   const float* __restrict__ Tp,
                                                   float* __restrict__ Tn,
                                                   float alpha, float beta) {
    const int t  = threadIdx.x;
    const int r0 = blockIdx.x * RPB;
    const __half* L0 = Lh + (size_t)r0 * NA;

    float acc[RPB][16];
    #pragma unroll
    for (int r = 0; r < RPB; ++r)
        #pragma unroll
        for (int j = 0; j < 16; ++j) acc[r][j] = 0.f;

    // prefetch iteration 0's Ls quads
    uint2 lp[RPB];
    {
        const int c4 = t * 4;
        #pragma unroll
        for (int r = 0; r < RPB; ++r)
            lp[r] = *(const uint2*)(L0 + (size_t)r * NA + c4);
    }

    #pragma unroll 1
    for (int it = 0; it < NA / (256 * 4); ++it) {   // 16 iterations
        const int c4 = (it * 256 + t) * 4;
        // consume prefetched Ls -> fp32
        float lf[RPB][4];
        #pragma unroll
        for (int r = 0; r < RPB; ++r) {
            uint2 v = lp[r];
            __half2 h01 = *reinterpret_cast<__half2*>(&v.x);
            __half2 h23 = *reinterpret_cast<__half2*>(&v.y);
            float2 f01 = __half22float2(h01);
            float2 f23 = __half22float2(h23);
            lf[r][0] = f01.x; lf[r][1] = f01.y;
            lf[r][2] = f23.x; lf[r][3] = f23.y;
        }
        // issue next iteration's Ls loads (stay in flight during FMAs)
        if (it < NA / (256 * 4) - 1) {
            const int c4n = c4 + 1024;
            #pragma unroll
            for (int r = 0; r < RPB; ++r)
                lp[r] = *(const uint2*)(L0 + (size_t)r * NA + c4n);
        }
        // T^T rows in two halves of 8 channels
        #pragma unroll
        for (int h = 0; h < 2; ++h) {
            float4 tv[8];
            #pragma unroll
            for (int jj = 0; jj < 8; ++jj)
                tv[jj] = *(const float4*)(Tt + (size_t)(h * 8 + jj) * NA + c4);
            #pragma unroll
            for (int cc = 0; cc < 4; ++cc)
                #pragma unroll
                for (int jj = 0; jj < 8; ++jj) {
                    const float tvj = f4_get(tv[jj], cc);
                    #pragma unroll
                    for (int r = 0; r < RPB; ++r)
                        acc[r][h * 8 + jj] = fmaf(lf[r][cc], tvj,
                                                  acc[r][h * 8 + jj]);
                }
        }
    }

    // reduce 256 threads -> RPB*16 sums
    __shared__ float red[4][RPB * 16];
    const int wave = t >> 6;
    const int lane = t & 63;
    #pragma unroll
    for (int r = 0; r < RPB; ++r)
        #pragma unroll
        for (int j = 0; j < 16; ++j) {
            float v = acc[r][j];
            #pragma unroll
            for (int off = 32; off > 0; off >>= 1)
                v += __shfl_down(v, off, 64);
            if (lane == 0) red[wave][r * 16 + j] = v;
        }
    __syncthreads();
    if (t < RPB * 16) {
        const float s = red[0][t] + red[1][t] + red[2][t] + red[3][t];
        const int rr = t >> 4;
        const int jj = t & 15;
        float v = alpha * s;
        if (beta != 0.f) v += beta * Tp[(size_t)jj * NA + r0 + rr];
        Tn[(size_t)jj * NA + r0 + rr] = v;
    }
}

// out[n][co] (+)= sum_a sum_ci Tt[ci][a*NN+n] * W[(a*CIN+ci)*COUT + co]
__global__ __launch_bounds__(256) void k_proj_t(const float* __restrict__ Tt,
                                                const float* __restrict__ W,
                                                const float* __restrict__ bias,
                                                float* __restrict__ out, int add) {
    int idx = blockIdx.x * 256 + threadIdx.x;
    if (idx >= NN * COUT) return;
    const int n  = idx >> 5;
    const int co = idx & 31;
    float s = add ? out[idx] : bias[co];
    #pragma unroll
    for (int a = 0; a < NANG; ++a)
        #pragma unroll
        for (int ci = 0; ci < CIN; ++ci)
            s = fmaf(Tt[(size_t)ci * NA + a * NN + n],
                     W[(size_t)(a * CIN + ci) * COUT + co], s);
    out[idx] = s;
}

extern "C" void kernel_launch(void* const* d_in, const int* in_sizes, int n_in,
                              void* d_out, int out_size, void* d_ws, size_t ws_size,
                              hipStream_t stream) {
    const float* x    = (const float*)d_in[0];
    const float* Ls   = (const float*)d_in[1];
    const float* W    = (const float*)d_in[2];
    const float* bias = (const float*)d_in[3];
    float* out = (float*)d_out;
    float* ws  = (float*)d_ws;

    const size_t TSZ = (size_t)NA * CIN;           // 1 MiB each (floats)
    float* buf[3] = { ws, ws + TSZ, ws + 2 * TSZ };
    __half* Lh = (__half*)(ws + 3 * TSZ);          // 537 MB region in d_ws
    const int WSTRIDE = (NANG * CIN) * COUT;

    // one-time (per call) fp32 -> fp16 convert of Ls
    k_conv<<<4096, 256, 0, stream>>>(Ls, Lh);

    // k = 0
    k_tile_t<<<(CIN * NA + 255) / 256, 256, 0, stream>>>(x, buf[0]);
    k_proj_t<<<(NN * COUT + 255) / 256, 256, 0, stream>>>(buf[0], W, bias, out, 0);

    // k = 1 : T1 = Ls @ T0
    k_spmm_h<<<NA / RPB, 256, 0, stream>>>(Lh, buf[0], buf[0], buf[1], 1.f, 0.f);
    k_proj_t<<<(NN * COUT + 255) / 256, 256, 0, stream>>>(buf[1], W + WSTRIDE, bias, out, 1);

    // k = 2..14 : T2 = 2*(Ls @ T1) - T0
    int prev = 0, cur = 1;
    for (int k = 2; k < KCH; ++k) {
        int nxt = 3 - cur - prev;
        k_spmm_h<<<NA / RPB, 256, 0, stream>>>(Lh, buf[cur], buf[prev], buf[nxt], 2.f, -1.f);
        k_proj_t<<<(NN * COUT + 255) / 256, 256, 0, stream>>>(buf[nxt], W + (size_t)k * WSTRIDE,
                                                              bias, out, 1);
        prev = cur; cur = nxt;
    }
}

// Round 5
// 2928.299 us; speedup vs baseline: 3.9047x; 1.5515x over previous
//
#include <hip/hip_runtime.h>
#include <hip/hip_fp16.h>

#define NA   16384   // n_angles * N
#define NN   2048    // N
#define CIN  16
#define COUT 32
#define NANG 8
#define KCH  15
#define SPLITK 8
#define KSLICE (NA / SPLITK)     // 2048 K per wave
#define KSTEPS (KSLICE / 32)     // 64 MFMA steps per wave
#define CHUNK  4                 // K-steps per double-buffered chunk
#define NCHUNK (KSTEPS / CHUNK)  // 16

// T iterates grow to ~3e5 (Chebyshev blow-up off the real axis) -> fp16
// mirror is stored pre-scaled by 2^-5 (exact), alpha in combine folds it back.
#define TSCALE_INV 0.03125f
#define TSCALE     32.0f

typedef _Float16 f16x8 __attribute__((ext_vector_type(8)));
typedef float    f32x4 __attribute__((ext_vector_type(4)));

// Build T0^T (f32 [CIN][NA]) + scaled fp16 mirror
__global__ __launch_bounds__(256) void k_tile_t(const float* __restrict__ x,
                                                float* __restrict__ Tt0,
                                                _Float16* __restrict__ Tt0h) {
    int idx = blockIdx.x * 256 + threadIdx.x;
    if (idx >= CIN * NA) return;
    int j = idx >> 14;
    int c = idx & (NA - 1);
    int n = c & (NN - 1);
    float v = x[n * CIN + j];
    Tt0[idx] = v;
    Tt0h[idx] = (_Float16)(v * TSCALE_INV);
}

// MFMA spmm: parts[s][ch][pos] = (Ls-rows-panel x K-slice) @ T16
// CONV=1: A loaded fp32 from Ls, converted, fragment stored to Lh.
// CONV=0: A loaded fp16 from Lh.
// wave: 16-row panel p, split s; frag addressing: base + (l&15)*NA + (l>>4)*8
#define LOADCHUNK(BUF, C)                                                    \
    _Pragma("unroll")                                                        \
    for (int u = 0; u < CHUNK; ++u) {                                        \
        const int st = (C) * CHUNK + u;                                      \
        if (CONV) {                                                          \
            float4 f0 = *(const float4*)(aF + st * 32);                      \
            float4 f1 = *(const float4*)(aF + st * 32 + 4);                  \
            f16x8 h;                                                         \
            h[0] = (_Float16)f0.x; h[1] = (_Float16)f0.y;                    \
            h[2] = (_Float16)f0.z; h[3] = (_Float16)f0.w;                    \
            h[4] = (_Float16)f1.x; h[5] = (_Float16)f1.y;                    \
            h[6] = (_Float16)f1.z; h[7] = (_Float16)f1.w;                    \
            *(f16x8*)(aW + st * 32) = h;                                     \
            A[BUF][u] = h;                                                   \
        } else {                                                             \
            A[BUF][u] = *(const f16x8*)(aP + st * 32);                       \
        }                                                                    \
        B[BUF][u] = *(const f16x8*)(bP + st * 32);                           \
    }

template<int CONV>
__global__ __launch_bounds__(256, CONV ? 2 : 4)
void k_spmm_mfma(const float* __restrict__ Ls,
                 _Float16* __restrict__ Lh,
                 const _Float16* __restrict__ Th,   // [CIN][NA] fp16 (scaled)
                 float* __restrict__ parts) {       // [SPLITK][CIN][NA]
    const int w  = threadIdx.x >> 6;
    const int l  = threadIdx.x & 63;
    const int p  = blockIdx.x >> 1;                 // row panel 0..1023
    const int s  = ((blockIdx.x & 1) << 2) | w;     // split 0..7
    const int rc = l & 15;                          // A-row / B-channel
    const int kg = l >> 4;                          // k-group 0..3

    const size_t rbase = (size_t)(p * 16 + rc) * NA;
    const size_t kbase = (size_t)s * KSLICE + kg * 8;

    const _Float16* aP = Lh + rbase + kbase;
    _Float16*       aW = Lh + rbase + kbase;
    const float*    aF = Ls + rbase + kbase;
    const _Float16* bP = Th + (size_t)rc * NA + kbase;

    f32x4 acc = {0.f, 0.f, 0.f, 0.f};
    f16x8 A[2][CHUNK], B[2][CHUNK];

    LOADCHUNK(0, 0);
    #pragma unroll
    for (int c = 0; c < NCHUNK; ++c) {
        if (c + 1 < NCHUNK) {
            if ((c & 1) == 0) { LOADCHUNK(1, c + 1); }
            else             { LOADCHUNK(0, c + 1); }
        }
        #pragma unroll
        for (int u = 0; u < CHUNK; ++u)
            acc = __builtin_amdgcn_mfma_f32_16x16x32_f16(A[c & 1][u], B[c & 1][u], acc, 0, 0, 0);
    }

    // D: ch = l&15, pos-offset = (l>>4)*4 + i
    float* dst = parts + ((size_t)s * CIN + rc) * NA + p * 16 + kg * 4;
    #pragma unroll
    for (int i = 0; i < 4; ++i) dst[i] = acc[i];
}

// Tn = alpha * sum_s parts[s] + beta * Tp   (f32 master + scaled fp16 mirror)
// alpha already includes the *TSCALE unscaling of the fp16 operands.
__global__ __launch_bounds__(256) void k_combine(const float* __restrict__ parts,
                                                 const float* __restrict__ Tp,
                                                 float* __restrict__ Tn,
                                                 _Float16* __restrict__ Tnh,
                                                 float alpha, float beta) {
    int idx = blockIdx.x * 256 + threadIdx.x;
    if (idx >= CIN * NA) return;
    float sum = 0.f;
    #pragma unroll
    for (int k = 0; k < SPLITK; ++k)
        sum += parts[(size_t)k * (CIN * NA) + idx];
    float v = alpha * sum;
    if (beta != 0.f) v += beta * Tp[idx];
    Tn[idx] = v;
    Tnh[idx] = (_Float16)(v * TSCALE_INV);
}

// out[n][co] (+)= sum_a sum_ci Tt[ci][a*NN+n] * W[(a*CIN+ci)*COUT + co]
__global__ __launch_bounds__(256) void k_proj_t(const float* __restrict__ Tt,
                                                const float* __restrict__ W,
                                                const float* __restrict__ bias,
                                                float* __restrict__ out, int add) {
    int idx = blockIdx.x * 256 + threadIdx.x;
    if (idx >= NN * COUT) return;
    const int n  = idx >> 5;
    const int co = idx & 31;
    float s = add ? out[idx] : bias[co];
    #pragma unroll
    for (int a = 0; a < NANG; ++a)
        #pragma unroll
        for (int ci = 0; ci < CIN; ++ci)
            s = fmaf(Tt[(size_t)ci * NA + a * NN + n],
                     W[(size_t)(a * CIN + ci) * COUT + co], s);
    out[idx] = s;
}

extern "C" void kernel_launch(void* const* d_in, const int* in_sizes, int n_in,
                              void* d_out, int out_size, void* d_ws, size_t ws_size,
                              hipStream_t stream) {
    const float* x    = (const float*)d_in[0];
    const float* Ls   = (const float*)d_in[1];
    const float* W    = (const float*)d_in[2];
    const float* bias = (const float*)d_in[3];
    float* out = (float*)d_out;

    char* wsb = (char*)d_ws;
    _Float16* Lh = (_Float16*)wsb;                                  // 512 MiB
    float* parts = (float*)(wsb + (size_t)NA * NA * sizeof(_Float16));   // 8 MiB
    float* T32base = parts + (size_t)SPLITK * CIN * NA;
    const size_t TSZ = (size_t)CIN * NA;
    float* T32[3] = { T32base, T32base + TSZ, T32base + 2 * TSZ };
    _Float16* T16base = (_Float16*)(T32base + 3 * TSZ);
    _Float16* T16[3] = { T16base, T16base + TSZ, T16base + 2 * TSZ };

    const int WSTRIDE = (NANG * CIN) * COUT;
    const int PGRID = (NN * COUT + 255) / 256;
    const int CGRID = (CIN * NA + 255) / 256;

    // k = 0
    k_tile_t<<<CGRID, 256, 0, stream>>>(x, T32[0], T16[0]);
    k_proj_t<<<PGRID, 256, 0, stream>>>(T32[0], W, bias, out, 0);

    // k = 1 : T1 = Ls @ T0 ; fused fp32->fp16 conversion of Ls into Lh
    // (operands carry 1/32 scale -> alpha = 32)
    k_spmm_mfma<1><<<2048, 256, 0, stream>>>(Ls, Lh, T16[0], parts);
    k_combine<<<CGRID, 256, 0, stream>>>(parts, T32[0], T32[1], T16[1],
                                         TSCALE, 0.f);
    k_proj_t<<<PGRID, 256, 0, stream>>>(T32[1], W + WSTRIDE, bias, out, 1);

    // k = 2..14 : T2 = 2*(Ls @ T1) - T0  -> alpha = 2*32, beta = -1
    int prev = 0, cur = 1;
    for (int k = 2; k < KCH; ++k) {
        int nxt = 3 - cur - prev;
        k_spmm_mfma<0><<<2048, 256, 0, stream>>>(Ls, Lh, T16[cur], parts);
        k_combine<<<CGRID, 256, 0, stream>>>(parts, T32[prev], T32[nxt], T16[nxt],
                                             2.0f * TSCALE, -1.f);
        k_proj_t<<<PGRID, 256, 0, stream>>>(T32[nxt], W + (size_t)k * WSTRIDE, bias, out, 1);
        prev = cur; cur = nxt;
    }
}

// Round 6
// 2417.920 us; speedup vs baseline: 4.7289x; 1.2111x over previous
//
#include <hip/hip_runtime.h>
#include <hip/hip_fp16.h>

#define NA   16384   // n_angles * N
#define NN   2048    // N
#define CIN  16
#define COUT 32
#define NANG 8
#define KCH  15
#define SPLITK 8
#define KSLICE (NA / SPLITK)     // 2048 K per wave
#define KSTEPS (KSLICE / 32)     // 64 MFMA steps per wave
#define CHUNK  4                 // K-steps per double-buffered chunk
#define NCHUNK (KSTEPS / CHUNK)  // 16

// T iterates grow to ~3e5 -> fp16 mirror stored pre-scaled by 2^-5 (exact).
#define TSCALE_INV 0.03125f
#define TSCALE     32.0f

// Swizzled fragment layouts (written by us, read fully coalesced):
//  Lsw[(p*8+s)][st][l][8]  : 1024*8 regions x 64 steps x 64 lanes x 8 halves
//  Tsw[s][st][l][8]        : 8 regions x 64 x 64 x 8 halves (512 KiB / buffer)
// Fragment semantics (verified in round 5): for wave (p,s), lane l (rc=l&15,
// kg=l>>4), step st: A = Ls[p*16+rc][s*2048 + kg*8 + st*32 .. +7],
//                    B = T [rc]      [s*2048 + kg*8 + st*32 .. +7]

typedef _Float16 f16x8 __attribute__((ext_vector_type(8)));
typedef float    f32x4 __attribute__((ext_vector_type(4)));

// Build T0: f32 master [CIN][NA] + swizzled scaled fp16 mirror.
// One thread per (s,st,l) fragment -> 8 contiguous halves + 8 contiguous f32.
__global__ __launch_bounds__(256) void k_tile_t(const float* __restrict__ x,
                                                float* __restrict__ T32,
                                                _Float16* __restrict__ Tsw) {
    int tid = blockIdx.x * 256 + threadIdx.x;       // 0 .. 32767
    if (tid >= 8 * 64 * 64) return;
    const int s  = tid >> 12;
    const int st = (tid >> 6) & 63;
    const int l  = tid & 63;
    const int ch = l & 15;
    const int c2 = ((l >> 4) << 3) + (st << 5);     // kg*8 + st*32, 0..2040
    // n = (s*2048 + c2) % NN == c2  (slice size == NN)
    f16x8 h;
    float v[8];
    #pragma unroll
    for (int e = 0; e < 8; ++e) {
        v[e] = x[(c2 + e) * CIN + ch];
        h[e] = (_Float16)(v[e] * TSCALE_INV);
    }
    float* d = T32 + (size_t)ch * NA + s * KSLICE + c2;
    *(float4*)(d)     = make_float4(v[0], v[1], v[2], v[3]);
    *(float4*)(d + 4) = make_float4(v[4], v[5], v[6], v[7]);
    *(f16x8*)(Tsw + (size_t)tid * 8) = h;
}

// MFMA spmm. CONV=1: A from fp32 Ls (original layout), converted + written to
// Lsw in fragment order. CONV=0: A streamed contiguously from Lsw.
#define LOADCHUNK(BUF, C)                                                    \
    _Pragma("unroll")                                                        \
    for (int u = 0; u < CHUNK; ++u) {                                        \
        const int st = (C) * CHUNK + u;                                      \
        if (CONV) {                                                          \
            float4 f0 = *(const float4*)(aF + st * 32);                      \
            float4 f1 = *(const float4*)(aF + st * 32 + 4);                  \
            f16x8 h;                                                         \
            h[0] = (_Float16)f0.x; h[1] = (_Float16)f0.y;                    \
            h[2] = (_Float16)f0.z; h[3] = (_Float16)f0.w;                    \
            h[4] = (_Float16)f1.x; h[5] = (_Float16)f1.y;                    \
            h[6] = (_Float16)f1.z; h[7] = (_Float16)f1.w;                    \
            *(f16x8*)(aW + st * 512) = h;                                    \
            A[BUF][u] = h;                                                   \
        } else {                                                             \
            A[BUF][u] = *(const f16x8*)(aP + st * 512);                      \
        }                                                                    \
        B[BUF][u] = *(const f16x8*)(bP + st * 512);                          \
    }

template<int CONV>
__global__ __launch_bounds__(256, CONV ? 2 : 4)
void k_spmm_mfma(const float* __restrict__ Ls,
                 _Float16* __restrict__ Lsw,
                 const _Float16* __restrict__ Tsw,
                 float* __restrict__ parts) {       // [SPLITK][CIN][NA]
    const int w  = threadIdx.x >> 6;
    const int l  = threadIdx.x & 63;
    const int p  = blockIdx.x >> 1;                 // row panel 0..1023
    const int s  = ((blockIdx.x & 1) << 2) | w;     // split 0..7
    const int rc = l & 15;
    const int kg = l >> 4;

    const size_t abase = ((size_t)(p * 8 + s)) * (64 * 64 * 8) + (size_t)l * 8;
    const _Float16* aP = Lsw + abase;
    _Float16*       aW = Lsw + abase;
    const float*    aF = Ls + (size_t)(p * 16 + rc) * NA + s * KSLICE + kg * 8;
    const _Float16* bP = Tsw + (size_t)s * (64 * 64 * 8) + (size_t)l * 8;

    f32x4 acc = {0.f, 0.f, 0.f, 0.f};
    f16x8 A[2][CHUNK], B[2][CHUNK];

    LOADCHUNK(0, 0);
    #pragma unroll
    for (int c = 0; c < NCHUNK; ++c) {
        if (c + 1 < NCHUNK) {
            if ((c & 1) == 0) { LOADCHUNK(1, c + 1); }
            else             { LOADCHUNK(0, c + 1); }
        }
        #pragma unroll
        for (int u = 0; u < CHUNK; ++u)
            acc = __builtin_amdgcn_mfma_f32_16x16x32_f16(A[c & 1][u], B[c & 1][u], acc, 0, 0, 0);
    }

    // D: ch = rc, pos-offset = kg*4 + i
    float* dst = parts + ((size_t)s * CIN + rc) * NA + p * 16 + kg * 4;
    #pragma unroll
    for (int i = 0; i < 4; ++i) dst[i] = acc[i];
}

// Tn = alpha * sum_s parts[s] + beta * Tp ; writes f32 master + swizzled fp16.
// One thread per (s,st,l) fragment; all accesses 16-32B contiguous per lane.
__global__ __launch_bounds__(256) void k_combine(const float* __restrict__ parts,
                                                 const float* __restrict__ Tp,
                                                 float* __restrict__ Tn,
                                                 _Float16* __restrict__ Tsw,
                                                 float alpha, float beta) {
    int tid = blockIdx.x * 256 + threadIdx.x;       // 0 .. 32767
    if (tid >= 8 * 64 * 64) return;
    const int s  = tid >> 12;
    const int st = (tid >> 6) & 63;
    const int l  = tid & 63;
    const int ch = l & 15;
    const int c2 = ((l >> 4) << 3) + (st << 5);
    const size_t base = (size_t)ch * NA + s * KSLICE + c2;

    float sum[8];
    #pragma unroll
    for (int e = 0; e < 8; ++e) sum[e] = 0.f;
    #pragma unroll
    for (int k = 0; k < SPLITK; ++k) {
        const float* pp = parts + (size_t)k * (CIN * NA) + base;
        float4 a = *(const float4*)(pp);
        float4 b = *(const float4*)(pp + 4);
        sum[0] += a.x; sum[1] += a.y; sum[2] += a.z; sum[3] += a.w;
        sum[4] += b.x; sum[5] += b.y; sum[6] += b.z; sum[7] += b.w;
    }
    float4 p0, p1;
    if (beta != 0.f) {
        p0 = *(const float4*)(Tp + base);
        p1 = *(const float4*)(Tp + base + 4);
    } else {
        p0 = make_float4(0, 0, 0, 0); p1 = p0;
    }
    float v[8];
    v[0] = alpha * sum[0] + beta * p0.x; v[1] = alpha * sum[1] + beta * p0.y;
    v[2] = alpha * sum[2] + beta * p0.z; v[3] = alpha * sum[3] + beta * p0.w;
    v[4] = alpha * sum[4] + beta * p1.x; v[5] = alpha * sum[5] + beta * p1.y;
    v[6] = alpha * sum[6] + beta * p1.z; v[7] = alpha * sum[7] + beta * p1.w;
    *(float4*)(Tn + base)     = make_float4(v[0], v[1], v[2], v[3]);
    *(float4*)(Tn + base + 4) = make_float4(v[4], v[5], v[6], v[7]);
    f16x8 h;
    #pragma unroll
    for (int e = 0; e < 8; ++e) h[e] = (_Float16)(v[e] * TSCALE_INV);
    *(f16x8*)(Tsw + (size_t)tid * 8) = h;
}

// out[n][co] (+)= sum_a sum_ci T32[ci][a*NN+n] * W[(a*CIN+ci)*COUT + co]
__global__ __launch_bounds__(256) void k_proj_t(const float* __restrict__ Tt,
                                                const float* __restrict__ W,
                                                const float* __restrict__ bias,
                                                float* __restrict__ out, int add) {
    int idx = blockIdx.x * 256 + threadIdx.x;
    if (idx >= NN * COUT) return;
    const int n  = idx >> 5;
    const int co = idx & 31;
    float s = add ? out[idx] : bias[co];
    #pragma unroll
    for (int a = 0; a < NANG; ++a)
        #pragma unroll
        for (int ci = 0; ci < CIN; ++ci)
            s = fmaf(Tt[(size_t)ci * NA + a * NN + n],
                     W[(size_t)(a * CIN + ci) * COUT + co], s);
    out[idx] = s;
}

extern "C" void kernel_launch(void* const* d_in, const int* in_sizes, int n_in,
                              void* d_out, int out_size, void* d_ws, size_t ws_size,
                              hipStream_t stream) {
    const float* x    = (const float*)d_in[0];
    const float* Ls   = (const float*)d_in[1];
    const float* W    = (const float*)d_in[2];
    const float* bias = (const float*)d_in[3];
    float* out = (float*)d_out;

    char* wsb = (char*)d_ws;
    _Float16* Lsw = (_Float16*)wsb;                                   // 512 MiB
    float* parts = (float*)(wsb + (size_t)NA * NA * sizeof(_Float16)); // 8 MiB
    float* T32base = parts + (size_t)SPLITK * CIN * NA;
    const size_t TSZ = (size_t)CIN * NA;
    float* T32[3] = { T32base, T32base + TSZ, T32base + 2 * TSZ };
    _Float16* Tswbase = (_Float16*)(T32base + 3 * TSZ);
    _Float16* Tsw[3] = { Tswbase, Tswbase + TSZ, Tswbase + 2 * TSZ };

    const int WSTRIDE = (NANG * CIN) * COUT;
    const int PGRID = (NN * COUT + 255) / 256;
    const int FGRID = (8 * 64 * 64) / 256;          // 128 blocks

    // k = 0
    k_tile_t<<<FGRID, 256, 0, stream>>>(x, T32[0], Tsw[0]);
    k_proj_t<<<PGRID, 256, 0, stream>>>(T32[0], W, bias, out, 0);

    // k = 1 : T1 = Ls @ T0 ; fused fp32->fp16 conversion into swizzled Lsw
    k_spmm_mfma<1><<<2048, 256, 0, stream>>>(Ls, Lsw, Tsw[0], parts);
    k_combine<<<FGRID, 256, 0, stream>>>(parts, T32[0], T32[1], Tsw[1], TSCALE, 0.f);
    k_proj_t<<<PGRID, 256, 0, stream>>>(T32[1], W + WSTRIDE, bias, out, 1);

    // k = 2..14 : T2 = 2*(Ls @ T1) - T0   (alpha = 2*32, beta = -1)
    int prev = 0, cur = 1;
    for (int k = 2; k < KCH; ++k) {
        int nxt = 3 - cur - prev;
        k_spmm_mfma<0><<<2048, 256, 0, stream>>>(Ls, Lsw, Tsw[cur], parts);
        k_combine<<<FGRID, 256, 0, stream>>>(parts, T32[prev], T32[nxt], Tsw[nxt],
                                             2.0f * TSCALE, -1.f);
        k_proj_t<<<PGRID, 256, 0, stream>>>(T32[nxt], W + (size_t)k * WSTRIDE, bias, out, 1);
        prev = cur; cur = nxt;
    }
}

// Round 7
// 2278.068 us; speedup vs baseline: 5.0192x; 1.0614x over previous
//
#include <hip/hip_runtime.h>
#include <hip/hip_fp16.h>

#define NA   16384   // n_angles * N
#define NN   2048    // N
#define CIN  16
#define COUT 32
#define NANG 8
#define KCH  15
#define SPLITK 8
#define KSLICE (NA / SPLITK)     // 2048 K per wave
#define KSTEPS (KSLICE / 32)     // 64 MFMA steps per wave
#define CHUNK  4                 // K-steps per double-buffered chunk
#define NCHUNK (KSTEPS / CHUNK)  // 16
#define NPANEL 1024              // 16-row panels

// T iterates grow to ~3e5 -> fp16 mirror stored pre-scaled by 2^-5 (exact).
#define TSCALE_INV 0.03125f
#define TSCALE     32.0f

// Swizzled fragment layouts (written by us, read fully coalesced):
//  Lsw[(p*8+s)][st][l][8]  : 1024*8 regions x 64 steps x 64 lanes x 8 halves
//  Tsw[s][st][l][8]        : 8 regions x 64 x 64 x 8 halves (512 KiB / buffer)
// Fragment semantics: for wave (p,s), lane l (rc=l&15, kg=l>>4), step st:
//   A = Ls[p*16+rc][s*2048 + kg*8 + st*32 .. +7]
//   B = T [rc]      [s*2048 + kg*8 + st*32 .. +7]

typedef _Float16 f16x8 __attribute__((ext_vector_type(8)));
typedef float    f32x4 __attribute__((ext_vector_type(4)));

// Build T0: f32 master [CIN][NA] + swizzled scaled fp16 mirror.
__global__ __launch_bounds__(256) void k_tile_t(const float* __restrict__ x,
                                                float* __restrict__ T32,
                                                _Float16* __restrict__ Tsw) {
    int tid = blockIdx.x * 256 + threadIdx.x;       // 0 .. 32767
    if (tid >= 8 * 64 * 64) return;
    const int s  = tid >> 12;
    const int st = (tid >> 6) & 63;
    const int l  = tid & 63;
    const int ch = l & 15;
    const int c2 = ((l >> 4) << 3) + (st << 5);     // kg*8 + st*32, 0..2040
    f16x8 h;
    float v[8];
    #pragma unroll
    for (int e = 0; e < 8; ++e) {
        v[e] = x[(c2 + e) * CIN + ch];
        h[e] = (_Float16)(v[e] * TSCALE_INV);
    }
    float* d = T32 + (size_t)ch * NA + s * KSLICE + c2;
    *(float4*)(d)     = make_float4(v[0], v[1], v[2], v[3]);
    *(float4*)(d + 4) = make_float4(v[4], v[5], v[6], v[7]);
    *(f16x8*)(Tsw + (size_t)tid * 8) = h;
}

// MFMA spmm. CONV=1: A from fp32 Ls, converted + written to Lsw fragment-order.
// CONV=0: A streamed contiguously from Lsw.
// REV=1: reverse panel order (L3 ping-pong: consecutive sweeps stream Lsw in
// opposite directions so each sweep opens on the ~256MiB the last one left in
// L3; pure block remap, bitwise-identical math).
#define LOADCHUNK(BUF, C)                                                    \
    _Pragma("unroll")                                                        \
    for (int u = 0; u < CHUNK; ++u) {                                        \
        const int st = (C) * CHUNK + u;                                      \
        if (CONV) {                                                          \
            float4 f0 = *(const float4*)(aF + st * 32);                      \
            float4 f1 = *(const float4*)(aF + st * 32 + 4);                  \
            f16x8 h;                                                         \
            h[0] = (_Float16)f0.x; h[1] = (_Float16)f0.y;                    \
            h[2] = (_Float16)f0.z; h[3] = (_Float16)f0.w;                    \
            h[4] = (_Float16)f1.x; h[5] = (_Float16)f1.y;                    \
            h[6] = (_Float16)f1.z; h[7] = (_Float16)f1.w;                    \
            *(f16x8*)(aW + st * 512) = h;                                    \
            A[BUF][u] = h;                                                   \
        } else {                                                             \
            A[BUF][u] = *(const f16x8*)(aP + st * 512);                      \
        }                                                                    \
        B[BUF][u] = *(const f16x8*)(bP + st * 512);                          \
    }

template<int CONV, int REV>
__global__ __launch_bounds__(256, CONV ? 2 : 4)
void k_spmm_mfma(const float* __restrict__ Ls,
                 _Float16* __restrict__ Lsw,
                 const _Float16* __restrict__ Tsw,
                 float* __restrict__ parts) {       // [SPLITK][CIN][NA]
    const int w  = threadIdx.x >> 6;
    const int l  = threadIdx.x & 63;
    const int bp = blockIdx.x >> 1;
    const int p  = REV ? (NPANEL - 1 - bp) : bp;    // row panel 0..1023
    const int s  = ((blockIdx.x & 1) << 2) | w;     // split 0..7
    const int rc = l & 15;
    const int kg = l >> 4;

    const size_t abase = ((size_t)(p * 8 + s)) * (64 * 64 * 8) + (size_t)l * 8;
    const _Float16* aP = Lsw + abase;
    _Float16*       aW = Lsw + abase;
    const float*    aF = Ls + (size_t)(p * 16 + rc) * NA + s * KSLICE + kg * 8;
    const _Float16* bP = Tsw + (size_t)s * (64 * 64 * 8) + (size_t)l * 8;

    f32x4 acc = {0.f, 0.f, 0.f, 0.f};
    f16x8 A[2][CHUNK], B[2][CHUNK];

    LOADCHUNK(0, 0);
    #pragma unroll
    for (int c = 0; c < NCHUNK; ++c) {
        if (c + 1 < NCHUNK) {
            if ((c & 1) == 0) { LOADCHUNK(1, c + 1); }
            else             { LOADCHUNK(0, c + 1); }
        }
        #pragma unroll
        for (int u = 0; u < CHUNK; ++u)
            acc = __builtin_amdgcn_mfma_f32_16x16x32_f16(A[c & 1][u], B[c & 1][u], acc, 0, 0, 0);
    }

    // D: ch = rc, pos-offset = kg*4 + i ; contiguous 16B store
    float* dst = parts + ((size_t)s * CIN + rc) * NA + p * 16 + kg * 4;
    *(float4*)dst = make_float4(acc[0], acc[1], acc[2], acc[3]);
}

// Tn = alpha * sum_s parts[s] + beta * Tp ; writes f32 master + swizzled fp16.
__global__ __launch_bounds__(256) void k_combine(const float* __restrict__ parts,
                                                 const float* __restrict__ Tp,
                                                 float* __restrict__ Tn,
                                                 _Float16* __restrict__ Tsw,
                                                 float alpha, float beta) {
    int tid = blockIdx.x * 256 + threadIdx.x;       // 0 .. 32767
    if (tid >= 8 * 64 * 64) return;
    const int s  = tid >> 12;
    const int st = (tid >> 6) & 63;
    const int l  = tid & 63;
    const int ch = l & 15;
    const int c2 = ((l >> 4) << 3) + (st << 5);
    const size_t base = (size_t)ch * NA + s * KSLICE + c2;

    float sum[8];
    #pragma unroll
    for (int e = 0; e < 8; ++e) sum[e] = 0.f;
    #pragma unroll
    for (int k = 0; k < SPLITK; ++k) {
        const float* pp = parts + (size_t)k * (CIN * NA) + base;
        float4 a = *(const float4*)(pp);
        float4 b = *(const float4*)(pp + 4);
        sum[0] += a.x; sum[1] += a.y; sum[2] += a.z; sum[3] += a.w;
        sum[4] += b.x; sum[5] += b.y; sum[6] += b.z; sum[7] += b.w;
    }
    float4 p0, p1;
    if (beta != 0.f) {
        p0 = *(const float4*)(Tp + base);
        p1 = *(const float4*)(Tp + base + 4);
    } else {
        p0 = make_float4(0, 0, 0, 0); p1 = p0;
    }
    float v[8];
    v[0] = alpha * sum[0] + beta * p0.x; v[1] = alpha * sum[1] + beta * p0.y;
    v[2] = alpha * sum[2] + beta * p0.z; v[3] = alpha * sum[3] + beta * p0.w;
    v[4] = alpha * sum[4] + beta * p1.x; v[5] = alpha * sum[5] + beta * p1.y;
    v[6] = alpha * sum[6] + beta * p1.z; v[7] = alpha * sum[7] + beta * p1.w;
    *(float4*)(Tn + base)     = make_float4(v[0], v[1], v[2], v[3]);
    *(float4*)(Tn + base + 4) = make_float4(v[4], v[5], v[6], v[7]);
    f16x8 h;
    #pragma unroll
    for (int e = 0; e < 8; ++e) h[e] = (_Float16)(v[e] * TSCALE_INV);
    *(f16x8*)(Tsw + (size_t)tid * 8) = h;
}

// out[n][co] (+)= sum_a sum_ci T32[ci][a*NN+n] * W[(a*CIN+ci)*COUT + co]
__global__ __launch_bounds__(256) void k_proj_t(const float* __restrict__ Tt,
                                                const float* __restrict__ W,
                                                const float* __restrict__ bias,
                                                float* __restrict__ out, int add) {
    int idx = blockIdx.x * 256 + threadIdx.x;
    if (idx >= NN * COUT) return;
    const int n  = idx >> 5;
    const int co = idx & 31;
    float s = add ? out[idx] : bias[co];
    #pragma unroll
    for (int a = 0; a < NANG; ++a)
        #pragma unroll
        for (int ci = 0; ci < CIN; ++ci)
            s = fmaf(Tt[(size_t)ci * NA + a * NN + n],
                     W[(size_t)(a * CIN + ci) * COUT + co], s);
    out[idx] = s;
}

extern "C" void kernel_launch(void* const* d_in, const int* in_sizes, int n_in,
                              void* d_out, int out_size, void* d_ws, size_t ws_size,
                              hipStream_t stream) {
    const float* x    = (const float*)d_in[0];
    const float* Ls   = (const float*)d_in[1];
    const float* W    = (const float*)d_in[2];
    const float* bias = (const float*)d_in[3];
    float* out = (float*)d_out;

    char* wsb = (char*)d_ws;
    _Float16* Lsw = (_Float16*)wsb;                                   // 512 MiB
    float* parts = (float*)(wsb + (size_t)NA * NA * sizeof(_Float16)); // 8 MiB
    float* T32base = parts + (size_t)SPLITK * CIN * NA;
    const size_t TSZ = (size_t)CIN * NA;
    float* T32[3] = { T32base, T32base + TSZ, T32base + 2 * TSZ };
    _Float16* Tswbase = (_Float16*)(T32base + 3 * TSZ);
    _Float16* Tsw[3] = { Tswbase, Tswbase + TSZ, Tswbase + 2 * TSZ };

    const int WSTRIDE = (NANG * CIN) * COUT;
    const int PGRID = (NN * COUT + 255) / 256;
    const int FGRID = (8 * 64 * 64) / 256;          // 128 blocks

    // k = 0
    k_tile_t<<<FGRID, 256, 0, stream>>>(x, T32[0], Tsw[0]);
    k_proj_t<<<PGRID, 256, 0, stream>>>(T32[0], W, bias, out, 0);

    // k = 1 : T1 = Ls @ T0 ; fused fp32->fp16 conversion into swizzled Lsw
    k_spmm_mfma<1, 0><<<2048, 256, 0, stream>>>(Ls, Lsw, Tsw[0], parts);
    k_combine<<<FGRID, 256, 0, stream>>>(parts, T32[0], T32[1], Tsw[1], TSCALE, 0.f);
    k_proj_t<<<PGRID, 256, 0, stream>>>(T32[1], W + WSTRIDE, bias, out, 1);

    // k = 2..14 : T2 = 2*(Ls @ T1) - T0   (alpha = 2*32, beta = -1)
    // alternate sweep direction: Lsw was written forward, so k=2 runs reversed
    int prev = 0, cur = 1;
    for (int k = 2; k < KCH; ++k) {
        int nxt = 3 - cur - prev;
        if (k & 1)
            k_spmm_mfma<0, 0><<<2048, 256, 0, stream>>>(Ls, Lsw, Tsw[cur], parts);
        else
            k_spmm_mfma<0, 1><<<2048, 256, 0, stream>>>(Ls, Lsw, Tsw[cur], parts);
        k_combine<<<FGRID, 256, 0, stream>>>(parts, T32[prev], T32[nxt], Tsw[nxt],
                                             2.0f * TSCALE, -1.f);
        k_proj_t<<<PGRID, 256, 0, stream>>>(T32[nxt], W + (size_t)k * WSTRIDE, bias, out, 1);
        prev = cur; cur = nxt;
    }
}